// Round 1
// baseline (120.194 us; speedup 1.0000x reference)
//
#include <hip/hip_runtime.h>

#define T_DIM 2048
#define B_DIM 8192
#define GAMMA 0.99f
#define NCHUNK 32
#define CHUNK_L (T_DIM / NCHUNK)   // 64 rows per chunk

// ---------------------------------------------------------------------------
// Pass 1: per (chunk, 4-column group) compute rho, a = v + rho*(rew - v),
// write rho -> d_out[rho slot], a -> d_out[vtrace slot] (temporarily),
// and the chunk-composite (A, B) such that out[cL] = A + B * out[(c+1)L].
// Extended definition: a[T-1] = v[T-1], b[T-1] = 0 (so out[T-1]=v[T-1]).
// ---------------------------------------------------------------------------
__global__ __launch_bounds__(256) void vtrace_pass1(
    const float* __restrict__ v, const float* __restrict__ rew,
    const float* __restrict__ tlp, const float* __restrict__ blp,
    float* __restrict__ out_a,      // d_out vtrace slot (temp: a)
    float* __restrict__ out_rho,    // d_out + T*B
    float* __restrict__ Aw, float* __restrict__ Bw)
{
    const int j   = blockIdx.x * blockDim.x + threadIdx.x;  // 0 .. B/4-1
    const int c   = blockIdx.y;
    const int col = j * 4;
    const int t_hi = (c + 1) * CHUNK_L - 1;
    const int t_lo = c * CHUNK_L;

    float4 A  = make_float4(0.f, 0.f, 0.f, 0.f);
    float4 Bc = make_float4(1.f, 1.f, 1.f, 1.f);

    int idx = t_hi * B_DIM + col;
    #pragma unroll 2
    for (int t = t_hi; t >= t_lo; --t, idx -= B_DIM) {
        const float4 v4 = *(const float4*)(v   + idx);
        const float4 r4 = *(const float4*)(rew + idx);
        const float4 t4 = *(const float4*)(tlp + idx);
        const float4 b4 = *(const float4*)(blp + idx);

        float4 rho;
        rho.x = fminf(1.f, __expf(t4.x - b4.x));
        rho.y = fminf(1.f, __expf(t4.y - b4.y));
        rho.z = fminf(1.f, __expf(t4.z - b4.z));
        rho.w = fminf(1.f, __expf(t4.w - b4.w));
        *(float4*)(out_rho + idx) = rho;

        float4 a4, bv;
        if (t == T_DIM - 1) {
            a4 = v4;
            bv = make_float4(0.f, 0.f, 0.f, 0.f);
        } else {
            a4.x = fmaf(rho.x, r4.x - v4.x, v4.x);
            a4.y = fmaf(rho.y, r4.y - v4.y, v4.y);
            a4.z = fmaf(rho.z, r4.z - v4.z, v4.z);
            a4.w = fmaf(rho.w, r4.w - v4.w, v4.w);
            bv.x = GAMMA * rho.x;
            bv.y = GAMMA * rho.y;
            bv.z = GAMMA * rho.z;
            bv.w = GAMMA * rho.w;
        }
        *(float4*)(out_a + idx) = a4;

        // composite update (backward scan): A <- a + b*A ; B <- b*B
        A.x = fmaf(bv.x, A.x, a4.x);
        A.y = fmaf(bv.y, A.y, a4.y);
        A.z = fmaf(bv.z, A.z, a4.z);
        A.w = fmaf(bv.w, A.w, a4.w);
        Bc.x *= bv.x; Bc.y *= bv.y; Bc.z *= bv.z; Bc.w *= bv.w;
    }

    const int widx = c * B_DIM + col;
    *(float4*)(Aw + widx) = A;
    *(float4*)(Bw + widx) = Bc;
}

// ---------------------------------------------------------------------------
// Pass 1.5: per column, scan the NCHUNK composites right-to-left producing
// the carry each chunk needs in pass 2: cb[c] = out[(c+1)*L].
// ---------------------------------------------------------------------------
__global__ __launch_bounds__(256) void vtrace_carry(
    const float* __restrict__ Aw, const float* __restrict__ Bw,
    float* __restrict__ cb)
{
    const int j = blockIdx.x * blockDim.x + threadIdx.x;  // 0 .. B-1
    float x = 0.f;
    #pragma unroll
    for (int c = NCHUNK - 1; c >= 0; --c) {
        const int i = c * B_DIM + j;
        const float Av = Aw[i];
        const float Bv = Bw[i];
        cb[i] = x;
        x = fmaf(Bv, x, Av);
    }
}

// ---------------------------------------------------------------------------
// Pass 2: per (chunk, 4-column group) apply the recurrence within the chunk,
// reading a (from vtrace slot) and rho, writing vtrace in place.
// ---------------------------------------------------------------------------
__global__ __launch_bounds__(256) void vtrace_pass2(
    float* __restrict__ out_v,           // a in, vtrace out (in place)
    const float* __restrict__ rho_arr,
    const float* __restrict__ cb)
{
    const int j   = blockIdx.x * blockDim.x + threadIdx.x;  // 0 .. B/4-1
    const int c   = blockIdx.y;
    const int col = j * 4;
    const int t_hi = (c + 1) * CHUNK_L - 1;
    const int t_lo = c * CHUNK_L;

    float4 carry = *(const float4*)(cb + c * B_DIM + col);

    int idx = t_hi * B_DIM + col;
    #pragma unroll 2
    for (int t = t_hi; t >= t_lo; --t, idx -= B_DIM) {
        const float4 a4  = *(const float4*)(out_v  + idx);
        const float4 rho = *(const float4*)(rho_arr + idx);
        const float g = (t == T_DIM - 1) ? 0.f : GAMMA;
        float4 o;
        o.x = fmaf(g * rho.x, carry.x, a4.x);
        o.y = fmaf(g * rho.y, carry.y, a4.y);
        o.z = fmaf(g * rho.z, carry.z, a4.z);
        o.w = fmaf(g * rho.w, carry.w, a4.w);
        *(float4*)(out_v + idx) = o;
        carry = o;
    }
}

extern "C" void kernel_launch(void* const* d_in, const int* in_sizes, int n_in,
                              void* d_out, int out_size, void* d_ws, size_t ws_size,
                              hipStream_t stream) {
    const float* v   = (const float*)d_in[0];
    const float* rew = (const float*)d_in[1];
    const float* tlp = (const float*)d_in[2];
    const float* blp = (const float*)d_in[3];

    float* out_v   = (float*)d_out;                          // vtrace slot
    float* out_rho = out_v + (size_t)T_DIM * B_DIM;          // rhos slot

    float* Aw = (float*)d_ws;                                // NCHUNK*B floats
    float* Bw = Aw + (size_t)NCHUNK * B_DIM;                 // NCHUNK*B floats
    float* cb = Bw + (size_t)NCHUNK * B_DIM;                 // NCHUNK*B floats

    dim3 blk(256);
    dim3 grid_main(B_DIM / 4 / 256, NCHUNK);                 // (8, 32)

    vtrace_pass1<<<grid_main, blk, 0, stream>>>(v, rew, tlp, blp,
                                                out_v, out_rho, Aw, Bw);
    vtrace_carry<<<dim3(B_DIM / 256), blk, 0, stream>>>(Aw, Bw, cb);
    vtrace_pass2<<<grid_main, blk, 0, stream>>>(out_v, out_rho, cb);
}